// Round 14
// baseline (119.616 us; speedup 1.0000x reference)
//
#include <hip/hip_runtime.h>
#include <math.h>

// Problem constants
#define DIM   256
#define NST   256
#define LSEQ  512
#define BAT   2
#define DTSZ  64
#define PCOLS 576
#define NROWS 1024

constexpr float LOG2E = 1.4426950408889634f;

__device__ __forceinline__ float fexp2(float v) {
#if __has_builtin(__builtin_amdgcn_exp2f)
    return __builtin_amdgcn_exp2f(v);
#else
    return exp2f(v);
#endif
}

__device__ __forceinline__ float softplusf(float v) {
    return (v > 20.f) ? v : log1pf(__expf(v));
}

// LDS-only barrier: wait LDS ops, leave VMEM in flight across s_barrier.
__device__ __forceinline__ void barrier_lds_only() {
    __builtin_amdgcn_s_waitcnt(0xC07F);   // vmcnt=63, expcnt=7, lgkmcnt=0
    __builtin_amdgcn_s_barrier();
}

// Pack (beta, gamma) as bf16x2 in one dword: beta lo16, gamma hi16. RNE.
__device__ __forceinline__ unsigned pack_bg(float be, float ga) {
    unsigned ub = __float_as_uint(be);
    unsigned ug = __float_as_uint(ga);
    ub = (ub + 0x7fffu + ((ub >> 16) & 1u)) >> 16;
    ug = (ug + 0x7fffu + ((ug >> 16) & 1u)) & 0xffff0000u;
    return ub | ug;
}

// ---------------- proj: x@W_in (+ dt GEMM + softplus + dt*x). 512 blocks x 256.
// (verified since R6; betgam packing verified R11 — unchanged)
__global__ __launch_bounds__(256) void proj_kernel(
    const float* __restrict__ x, const float* __restrict__ W_in,
    const float* __restrict__ W_dt, const float* __restrict__ b_dt,
    unsigned* __restrict__ betgam,     // [NROWS, NST] bf16x2
    float* __restrict__ dtp, float* __restrict__ dtxp)
{
    __shared__ float xs[2][DIM];
    __shared__ float draw[2][DTSZ];
    const int j = threadIdx.x;
    const int row0 = blockIdx.x * 2;

    #pragma unroll
    for (int r = 0; r < 2; ++r) xs[r][j] = x[(row0 + r) * DIM + j];
    __syncthreads();

    float acc0[2] = {0.f, 0.f}, acc1[2] = {0.f, 0.f}, acc2[2] = {0.f, 0.f};
    const bool has2 = (j < 64);

    for (int kk = 0; kk < DIM; kk += 16) {
        float w0[16], w1[16], w2[16];
        #pragma unroll
        for (int u = 0; u < 16; ++u) {
            const int k = kk + u;
            w0[u] = W_in[k * PCOLS + j];
            w1[u] = W_in[k * PCOLS + 256 + j];
            w2[u] = has2 ? W_in[k * PCOLS + 512 + j] : 0.f;
        }
        #pragma unroll
        for (int r = 0; r < 2; ++r) {
            #pragma unroll
            for (int q = 0; q < 4; ++q) {
                float4 xv = *(const float4*)&xs[r][kk + q * 4];
                const float xa[4] = {xv.x, xv.y, xv.z, xv.w};
                #pragma unroll
                for (int u = 0; u < 4; ++u) {
                    const int uu = q * 4 + u;
                    acc0[r] = fmaf(xa[u], w0[uu], acc0[r]);
                    acc1[r] = fmaf(xa[u], w1[uu], acc1[r]);
                    acc2[r] = fmaf(xa[u], w2[uu], acc2[r]);
                }
            }
        }
    }

    #pragma unroll
    for (int r = 0; r < 2; ++r) {
        const int row = row0 + r;
        if (has2) {
            draw[r][j] = acc0[r];
            betgam[row * NST + 192 + j] = pack_bg(acc1[r], acc2[r]);
        } else {
            betgam[row * NST + (j - 64)] = pack_bg(acc0[r], acc1[r]);
        }
    }
    __syncthreads();

    float bd = b_dt[j];
    float accd[2] = {bd, bd};
    #pragma unroll 16
    for (int k = 0; k < DTSZ; ++k) {
        float w = W_dt[k * DIM + j];
        #pragma unroll
        for (int r = 0; r < 2; ++r) accd[r] = fmaf(draw[r][k], w, accd[r]);
    }
    #pragma unroll
    for (int r = 0; r < 2; ++r) {
        const int row = row0 + r;
        float sp = softplusf(accd[r]);
        dtp[row * DIM + j]  = sp;
        dtxp[row * DIM + j] = sp * xs[r][j];
    }
}

// ---------------- scan1p: R13 kernel with ONE change: __launch_bounds__(256, 2).
// R13's VGPR_Count=64 proved the compiler targeted 8 waves/SIMD (unreachable:
// grid=512 -> 2 blocks/CU) and collapsed the 6-window prefetch pipeline to fit.
// Declaring the TRUE occupancy (2 waves/SIMD) raises the cap to ~256 VGPRs so
// the 8x8 bg rotation + 48 in-flight loads can exist in registers.
__global__ __launch_bounds__(256, 2) void scan1p(
    const float* __restrict__ x,            // [NROWS, DIM]
    const float* __restrict__ alpha_log,    // [DIM, NST]
    const float* __restrict__ delta,        // [DIM]
    const unsigned* __restrict__ betgam,    // [NROWS, NST] packed
    const float* __restrict__ dtp,          // [NROWS, DIM]
    const float* __restrict__ dtxp,         // [NROWS, DIM]
    float* __restrict__ out)                // [NROWS, DIM]
{
    __shared__ float part[32][NST];         // 32 KB
    __shared__ float dts[LSEQ], dxs[LSEQ], xcol[LSEQ];   // 3 x 2 KB
    const int n = threadIdx.x;
    // XCD swizzle (R10-verified): XCDs 0-3 -> b=0, 4-7 -> b=1.
    const int xcd  = blockIdx.x & 7;
    const int slot = blockIdx.x >> 3;       // 0..63
    const int b = xcd >> 2;
    const int d = slot * 4 + (xcd & 3);
    const int rb = b * LSEQ;

    #pragma unroll
    for (int it = 0; it < 2; ++it) {
        const int l = n + it * 256;
        dts[l]  = dtp [(rb + l) * DIM + d];
        dxs[l]  = dtxp[(rb + l) * DIM + d];
        xcol[l] = x   [(rb + l) * DIM + d];
    }
    const float aln = -__expf(alpha_log[d * NST + n]) * LOG2E;
    const float dv  = delta[d];
    __syncthreads();                        // staging dep (global->LDS)

    float s = 0.f;
    unsigned bg[8][8];                      // 8-slot rotation, 6 windows ahead
    #pragma unroll
    for (int pw = 0; pw < 6; ++pw) {
        #pragma unroll
        for (int t = 0; t < 8; ++t)
            bg[pw][t] = betgam[(rb + pw * 8 + t) * NST + n];
    }

    #pragma unroll 8
    for (int w = 0; w < 64; ++w) {
        const int cur = w & 7;
        const int pf  = (w + 6) & 7;
        if (w + 6 < 64) {                   // issue window w+6 while computing w
            #pragma unroll
            for (int t = 0; t < 8; ++t)
                bg[pf][t] = betgam[(rb + (w + 6) * 8 + t) * NST + n];
        }
        float4 dta = *(const float4*)&dts[w * 8];
        float4 dtb = *(const float4*)&dts[w * 8 + 4];
        float4 dxa = *(const float4*)&dxs[w * 8];
        float4 dxb = *(const float4*)&dxs[w * 8 + 4];
        const float dtw[8] = {dta.x, dta.y, dta.z, dta.w, dtb.x, dtb.y, dtb.z, dtb.w};
        const float dxw[8] = {dxa.x, dxa.y, dxa.z, dxa.w, dxb.x, dxb.y, dxb.z, dxb.w};

        const int prow = (w & 3) * 8;
        #pragma unroll
        for (int t = 0; t < 8; ++t) {
            const unsigned u = bg[cur][t];
            const float be = __uint_as_float(u << 16);
            const float ga = __uint_as_float(u & 0xffff0000u);
            float a = fexp2(dtw[t] * aln);
            s = fmaf(a, s, dxw[t] * be);
            part[prow + t][n] = s * ga;     // 2-way bank alias: free
        }

        if ((w & 3) == 3) {                 // every 32 steps: reduce 32 rows x 256
            barrier_lds_only();
            const int trow = n >> 3, seg = n & 7;
            float sum = 0.f;
            #pragma unroll
            for (int k = 0; k < 32; ++k)
                sum += part[trow][seg * 32 + ((k + n) & 31)];   // measured 0-conflict
            sum += __shfl_xor(sum, 1);
            sum += __shfl_xor(sum, 2);
            sum += __shfl_xor(sum, 4);
            if (seg == 0) {
                const int l = (w >> 2) * 32 + trow;
                out[(rb + l) * DIM + d] = sum + xcol[l] * dv;
            }
            barrier_lds_only();             // WAR before next window's writes
        }
    }
}

extern "C" void kernel_launch(void* const* d_in, const int* in_sizes, int n_in,
                              void* d_out, int out_size, void* d_ws, size_t ws_size,
                              hipStream_t stream) {
    const float* x         = (const float*)d_in[0];
    const float* W_in      = (const float*)d_in[1];
    const float* W_dt      = (const float*)d_in[2];
    const float* b_dt      = (const float*)d_in[3];
    const float* alpha_log = (const float*)d_in[4];
    const float* delta     = (const float*)d_in[5];
    float* out = (float*)d_out;

    // Workspace: betgam 1MB + dtp/dtxp 2MB = 3 MB
    unsigned* betgam = (unsigned*)d_ws;
    float* dtp  = (float*)(betgam + NROWS * NST);
    float* dtxp = dtp + NROWS * DIM;

    proj_kernel<<<NROWS / 2, 256, 0, stream>>>(x, W_in, W_dt, b_dt, betgam, dtp, dtxp);
    scan1p<<<BAT * DIM, 256, 0, stream>>>(x, alpha_log, delta, betgam, dtp, dtxp, out);
}

// Round 15
// 119.230 us; speedup vs baseline: 1.0032x; 1.0032x over previous
//
#include <hip/hip_runtime.h>
#include <math.h>

// Problem constants
#define DIM   256
#define NST   256
#define LSEQ  512
#define BAT   2
#define DTSZ  64
#define PCOLS 576
#define NROWS 1024

constexpr float LOG2E = 1.4426950408889634f;

__device__ __forceinline__ float fexp2(float v) {
#if __has_builtin(__builtin_amdgcn_exp2f)
    return __builtin_amdgcn_exp2f(v);
#else
    return exp2f(v);
#endif
}

__device__ __forceinline__ float softplusf(float v) {
    return (v > 20.f) ? v : log1pf(__expf(v));
}

// LDS-only barrier: wait LDS ops, leave VMEM in flight across s_barrier.
__device__ __forceinline__ void barrier_lds_only() {
    __builtin_amdgcn_s_waitcnt(0xC07F);   // vmcnt=63, expcnt=7, lgkmcnt=0
    __builtin_amdgcn_s_barrier();
}

// Pack (beta, gamma) as bf16x2: beta lo16, gamma hi16. RNE.
__device__ __forceinline__ unsigned pack_bg(float be, float ga) {
    unsigned ub = __float_as_uint(be);
    unsigned ug = __float_as_uint(ga);
    ub = (ub + 0x7fffu + ((ub >> 16) & 1u)) >> 16;
    ug = (ug + 0x7fffu + ((ug >> 16) & 1u)) & 0xffff0000u;
    return ub | ug;
}

// ---------------- proj: x@W_in (+ dt GEMM + softplus + dt*x). 512 blocks x 256.
// (verified since R6; betgam packing verified R11 — unchanged)
__global__ __launch_bounds__(256) void proj_kernel(
    const float* __restrict__ x, const float* __restrict__ W_in,
    const float* __restrict__ W_dt, const float* __restrict__ b_dt,
    unsigned* __restrict__ betgam,     // [NROWS, NST] bf16x2
    float* __restrict__ dtp, float* __restrict__ dtxp)
{
    __shared__ float xs[2][DIM];
    __shared__ float draw[2][DTSZ];
    const int j = threadIdx.x;
    const int row0 = blockIdx.x * 2;

    #pragma unroll
    for (int r = 0; r < 2; ++r) xs[r][j] = x[(row0 + r) * DIM + j];
    __syncthreads();

    float acc0[2] = {0.f, 0.f}, acc1[2] = {0.f, 0.f}, acc2[2] = {0.f, 0.f};
    const bool has2 = (j < 64);

    for (int kk = 0; kk < DIM; kk += 16) {
        float w0[16], w1[16], w2[16];
        #pragma unroll
        for (int u = 0; u < 16; ++u) {
            const int k = kk + u;
            w0[u] = W_in[k * PCOLS + j];
            w1[u] = W_in[k * PCOLS + 256 + j];
            w2[u] = has2 ? W_in[k * PCOLS + 512 + j] : 0.f;
        }
        #pragma unroll
        for (int r = 0; r < 2; ++r) {
            #pragma unroll
            for (int q = 0; q < 4; ++q) {
                float4 xv = *(const float4*)&xs[r][kk + q * 4];
                const float xa[4] = {xv.x, xv.y, xv.z, xv.w};
                #pragma unroll
                for (int u = 0; u < 4; ++u) {
                    const int uu = q * 4 + u;
                    acc0[r] = fmaf(xa[u], w0[uu], acc0[r]);
                    acc1[r] = fmaf(xa[u], w1[uu], acc1[r]);
                    acc2[r] = fmaf(xa[u], w2[uu], acc2[r]);
                }
            }
        }
    }

    #pragma unroll
    for (int r = 0; r < 2; ++r) {
        const int row = row0 + r;
        if (has2) {
            draw[r][j] = acc0[r];
            betgam[row * NST + 192 + j] = pack_bg(acc1[r], acc2[r]);
        } else {
            betgam[row * NST + (j - 64)] = pack_bg(acc0[r], acc1[r]);
        }
    }
    __syncthreads();

    float bd = b_dt[j];
    float accd[2] = {bd, bd};
    #pragma unroll 16
    for (int k = 0; k < DTSZ; ++k) {
        float w = W_dt[k * DIM + j];
        #pragma unroll
        for (int r = 0; r < 2; ++r) accd[r] = fmaf(draw[r][k], w, accd[r]);
    }
    #pragma unroll
    for (int r = 0; r < 2; ++r) {
        const int row = row0 + r;
        float sp = softplusf(accd[r]);
        dtp[row * DIM + j]  = sp;
        dtxp[row * DIM + j] = sp * xs[r][j];
    }
}

// ---------------- scan1p: producer-consumer wave specialization.
// 512 blocks x 512 threads. Waves 0-3 (tid<256, thread=n): R10-verified
// recurrence + 3-ahead prefetch, writing s*gamma to ping-pong part[2][32][256].
// Waves 4-7: verified 0-conflict transpose-reduction + epilogue stores.
// One s_barrier per 32-step super-iteration (16 total, was 32); reduction and
// output stores run CONCURRENTLY with the next 32 production steps.
__global__ __launch_bounds__(512, 4) void scan1p(
    const float* __restrict__ x,            // [NROWS, DIM]
    const float* __restrict__ alpha_log,    // [DIM, NST]
    const float* __restrict__ delta,        // [DIM]
    const unsigned* __restrict__ betgam,    // [NROWS, NST] packed
    const float* __restrict__ dtp,          // [NROWS, DIM]
    const float* __restrict__ dtxp,         // [NROWS, DIM]
    float* __restrict__ out)                // [NROWS, DIM]
{
    __shared__ float part[2][32][NST];      // 64 KB ping-pong
    __shared__ float dts[LSEQ], dxs[LSEQ], xcol[LSEQ];   // 6 KB
    const int tid = threadIdx.x;
    // XCD swizzle (R10-verified): XCDs 0-3 -> b=0, 4-7 -> b=1.
    const int xcd  = blockIdx.x & 7;
    const int slot = blockIdx.x >> 3;       // 0..63
    const int b = xcd >> 2;
    const int d = slot * 4 + (xcd & 3);
    const int rb = b * LSEQ;

    // Staging: 512 threads, one element of each array per thread.
    dts[tid]  = dtp [(rb + tid) * DIM + d];
    dxs[tid]  = dtxp[(rb + tid) * DIM + d];
    xcol[tid] = x   [(rb + tid) * DIM + d];
    const float dv = delta[d];
    __syncthreads();                        // staging dep (global->LDS)

    if (tid < 256) {
        // ================= PRODUCER (waves 0-3), thread = n =================
        const int n = tid;
        const float aln = -__expf(alpha_log[d * NST + n]) * LOG2E;
        float s = 0.f;
        unsigned bg[4][8];                  // 4-slot rotation, 3 windows ahead
        #pragma unroll
        for (int pw = 0; pw < 3; ++pw) {
            #pragma unroll
            for (int t = 0; t < 8; ++t)
                bg[pw][t] = betgam[(rb + pw * 8 + t) * NST + n];
        }

        for (int k = 0; k <= 16; ++k) {     // 16 production super-iterations + tail
            if (k < 16) {
                const int buf = k & 1;
                #pragma unroll
                for (int wi = 0; wi < 4; ++wi) {
                    const int w = k * 4 + wi;
                    const int cur = w & 3;
                    const int pf  = (w + 3) & 3;
                    if (w + 3 < 64) {
                        #pragma unroll
                        for (int t = 0; t < 8; ++t)
                            bg[pf][t] = betgam[(rb + (w + 3) * 8 + t) * NST + n];
                    }
                    float4 dta = *(const float4*)&dts[w * 8];
                    float4 dtb = *(const float4*)&dts[w * 8 + 4];
                    float4 dxa = *(const float4*)&dxs[w * 8];
                    float4 dxb = *(const float4*)&dxs[w * 8 + 4];
                    const float dtw[8] = {dta.x, dta.y, dta.z, dta.w,
                                          dtb.x, dtb.y, dtb.z, dtb.w};
                    const float dxw[8] = {dxa.x, dxa.y, dxa.z, dxa.w,
                                          dxb.x, dxb.y, dxb.z, dxb.w};
                    #pragma unroll
                    for (int t = 0; t < 8; ++t) {
                        const unsigned u = bg[cur][t];
                        const float be = __uint_as_float(u << 16);
                        const float ga = __uint_as_float(u & 0xffff0000u);
                        float a = fexp2(dtw[t] * aln);
                        s = fmaf(a, s, dxw[t] * be);
                        part[buf][wi * 8 + t][n] = s * ga;   // 2-way alias: free
                    }
                }
            }
            barrier_lds_only();             // publish buf k&1 / WAR vs k-2
        }
    } else {
        // ================= CONSUMER (waves 4-7) =================
        const int ct = tid - 256;           // 0..255
        const int trow = ct >> 3;           // 0..31 (step within super-iter)
        const int seg  = ct & 7;
        for (int k = 0; k <= 16; ++k) {
            if (k >= 1) {
                const int buf = (k - 1) & 1;
                float sum = 0.f;
                #pragma unroll
                for (int kk = 0; kk < 32; ++kk)
                    sum += part[buf][trow][seg * 32 + ((kk + ct) & 31)];  // 0-conflict
                sum += __shfl_xor(sum, 1);
                sum += __shfl_xor(sum, 2);
                sum += __shfl_xor(sum, 4);
                if (seg == 0) {
                    const int l = (k - 1) * 32 + trow;
                    out[(rb + l) * DIM + d] = sum + xcol[l] * dv;
                }
            }
            barrier_lds_only();
        }
    }
}

extern "C" void kernel_launch(void* const* d_in, const int* in_sizes, int n_in,
                              void* d_out, int out_size, void* d_ws, size_t ws_size,
                              hipStream_t stream) {
    const float* x         = (const float*)d_in[0];
    const float* W_in      = (const float*)d_in[1];
    const float* W_dt      = (const float*)d_in[2];
    const float* b_dt      = (const float*)d_in[3];
    const float* alpha_log = (const float*)d_in[4];
    const float* delta     = (const float*)d_in[5];
    float* out = (float*)d_out;

    // Workspace: betgam 1MB + dtp/dtxp 2MB = 3 MB
    unsigned* betgam = (unsigned*)d_ws;
    float* dtp  = (float*)(betgam + NROWS * NST);
    float* dtxp = dtp + NROWS * DIM;

    proj_kernel<<<NROWS / 2, 256, 0, stream>>>(x, W_in, W_dt, b_dt, betgam, dtp, dtxp);
    scan1p<<<BAT * DIM, 512, 0, stream>>>(x, alpha_log, delta, betgam, dtp, dtxp, out);
}